// Round 1
// baseline (679.500 us; speedup 1.0000x reference)
//
#include <hip/hip_runtime.h>

// NerTr fused pipeline for MI355X (gfx950).
// B=32, S=512, D=768, C=25.
// ws layout (floats): dec[32*25*768] @0, Wt[25*768] @614400, ner[32*512*25] @633600,
//                     csp[32*512*25] @1043200, llh[32] @1452800.
// out: [0]=loss (f32), [1 + b*512 + t] = viterbi tag (as f32).

#define NEGINF (-1e30f)

__device__ __forceinline__ float wsum(float v) {
#pragma unroll
  for (int m = 32; m >= 1; m >>= 1) v += __shfl_xor(v, m);
  return v;
}
__device__ __forceinline__ float wmax(float v) {
#pragma unroll
  for (int m = 32; m >= 1; m >>= 1) v = fmaxf(v, __shfl_xor(v, m));
  return v;
}

// ---------------- Kernel 1: LN(decoder_embedding) + transpose W ----------------
__global__ __launch_bounds__(256) void prep_kernel(
    const float* __restrict__ decemb, const float* __restrict__ gamma,
    const float* __restrict__ beta, const float* __restrict__ Wadd,
    float* __restrict__ dec, float* __restrict__ wt) {
  const int blk = blockIdx.x;
  const int tid = threadIdx.x;
  if (blk < 800) {  // one block per (b,c) row of decoder_embedding
    const float* in = decemb + (size_t)blk * 768;
    float x0 = in[tid], x1 = in[tid + 256], x2 = in[tid + 512];
    float s = x0 + x1 + x2, q = x0 * x0 + x1 * x1 + x2 * x2;
    float ws_ = wsum(s), wq = wsum(q);
    __shared__ float sa[4], sq[4];
    int w = tid >> 6, ln = tid & 63;
    if (ln == 0) { sa[w] = ws_; sq[w] = wq; }
    __syncthreads();
    float s1 = sa[0] + sa[1] + sa[2] + sa[3];
    float s2 = sq[0] + sq[1] + sq[2] + sq[3];
    float mean = s1 * (1.f / 768.f);
    float rstd = rsqrtf(s2 * (1.f / 768.f) - mean * mean + 1e-5f);
    float* o = dec + (size_t)blk * 768;
    o[tid]       = (x0 - mean) * rstd * gamma[tid]       + beta[tid];
    o[tid + 256] = (x1 - mean) * rstd * gamma[tid + 256] + beta[tid + 256];
    o[tid + 512] = (x2 - mean) * rstd * gamma[tid + 512] + beta[tid + 512];
  } else {  // transpose W_add [768,25] -> Wt [25,768]
    int gid = (blk - 800) * 256 + tid;
    for (int e = gid; e < 19200; e += 32 * 256) {
      int d = e / 25, j = e - d * 25;
      wt[j * 768 + d] = Wadd[e];
    }
  }
}

// ---------------- Kernel 2: softmax(cos_sim) blocks + fused LN/bmm/LN/logits ----------------
__global__ __launch_bounds__(256) void main_kernel(
    const float* __restrict__ bert, const float* __restrict__ oenc,
    const float* __restrict__ cosim, const float* __restrict__ gamma,
    const float* __restrict__ beta, const float* __restrict__ badd,
    const float* __restrict__ dec, const float* __restrict__ wt,
    float* __restrict__ ner, float* __restrict__ csp) {
  __shared__ float smem[4 * 64 * 29];  // per-wave logits reduce scratch (29 stride: odd vs 32 banks)
  const int tid = threadIdx.x;
  const int lane = tid & 63;
  const int wid = tid >> 6;
  const int blk = blockIdx.x;

  if (blk < 32) {
    // cos_sim_prob = softmax(cos_sim) for batch b (feeds Viterbi in scan_kernel)
    const int b = blk;
    for (int t = wid; t < 512; t += 4) {
      const float* cr = cosim + (size_t)(b * 512 + t) * 25;
      float v = (lane < 25) ? cr[lane] : NEGINF;
      float m = wmax(v);
      float e = __expf(v - m);
      float s = wsum(e);
      if (lane < 25) csp[(size_t)(b * 512 + t) * 25 + lane] = e / s;
    }
    return;
  }

  // ---- fused path: each wave owns 4 consecutive s-rows of one batch ----
  const int fblk = blk - 32;
  const int b = fblk >> 5;                         // 32 blocks per batch
  const int row0 = ((fblk & 31) << 4) + (wid << 2);
  const int rowg = b * 512 + row0;                 // global row index of wave's first row

  float g[12], bb[12];
#pragma unroll
  for (int k = 0; k < 3; k++) {
    float4 gv = *(const float4*)(gamma + (lane + (k << 6)) * 4);
    float4 bv = *(const float4*)(beta + (lane + (k << 6)) * 4);
    g[4 * k + 0] = gv.x; g[4 * k + 1] = gv.y; g[4 * k + 2] = gv.z; g[4 * k + 3] = gv.w;
    bb[4 * k + 0] = bv.x; bb[4 * k + 1] = bv.y; bb[4 * k + 2] = bv.z; bb[4 * k + 3] = bv.w;
  }

  float acc[4][12];  // holds bf, later emb (relu'd LN)
  // Phase A: bf = LN(bert)
#pragma unroll
  for (int r = 0; r < 4; r++) {
    const float* xp = bert + (size_t)(rowg + r) * 768;
    float x[12];
#pragma unroll
    for (int k = 0; k < 3; k++) {
      float4 v = *(const float4*)(xp + (lane + (k << 6)) * 4);
      x[4 * k] = v.x; x[4 * k + 1] = v.y; x[4 * k + 2] = v.z; x[4 * k + 3] = v.w;
    }
    float s = 0.f, q = 0.f;
#pragma unroll
    for (int e = 0; e < 12; e++) { s += x[e]; q += x[e] * x[e]; }
    s = wsum(s); q = wsum(q);
    float mean = s * (1.f / 768.f);
    float rstd = rsqrtf(q * (1.f / 768.f) - mean * mean + 1e-5f);
#pragma unroll
    for (int e = 0; e < 12; e++) acc[r][e] = (x[e] - mean) * rstd * g[e] + bb[e];
  }

  // Phase B: pq = cos_sim @ dec  (dec float4 loads amortized over 4 rows)
  float cs[4];
#pragma unroll
  for (int r = 0; r < 4; r++)
    cs[r] = (lane < 25) ? cosim[(size_t)(rowg + r) * 25 + lane] : 0.f;
  float pq[4][12];
#pragma unroll
  for (int r = 0; r < 4; r++)
#pragma unroll
    for (int e = 0; e < 12; e++) pq[r][e] = 0.f;
  const float* db = dec + (size_t)b * 25 * 768;
#pragma unroll 2
  for (int c = 0; c < 25; c++) {
    float dv[12];
#pragma unroll
    for (int k = 0; k < 3; k++) {
      float4 v = *(const float4*)(db + c * 768 + (lane + (k << 6)) * 4);
      dv[4 * k] = v.x; dv[4 * k + 1] = v.y; dv[4 * k + 2] = v.z; dv[4 * k + 3] = v.w;
    }
    float f0 = __shfl(cs[0], c), f1 = __shfl(cs[1], c);
    float f2 = __shfl(cs[2], c), f3 = __shfl(cs[3], c);
#pragma unroll
    for (int e = 0; e < 12; e++) {
      pq[0][e] = fmaf(f0, dv[e], pq[0][e]);
      pq[1][e] = fmaf(f1, dv[e], pq[1][e]);
      pq[2][e] = fmaf(f2, dv[e], pq[2][e]);
      pq[3][e] = fmaf(f3, dv[e], pq[3][e]);
    }
  }

  // Phase C: emb = relu(LN(bf + oenc + pq))
#pragma unroll
  for (int r = 0; r < 4; r++) {
    const float* op = oenc + (size_t)(rowg + r) * 768;
    float x[12];
#pragma unroll
    for (int k = 0; k < 3; k++) {
      float4 v = *(const float4*)(op + (lane + (k << 6)) * 4);
      x[4 * k] = v.x; x[4 * k + 1] = v.y; x[4 * k + 2] = v.z; x[4 * k + 3] = v.w;
    }
    float s = 0.f, q = 0.f;
#pragma unroll
    for (int e = 0; e < 12; e++) {
      x[e] += acc[r][e] + pq[r][e];
      s += x[e]; q += x[e] * x[e];
    }
    s = wsum(s); q = wsum(q);
    float mean = s * (1.f / 768.f);
    float rstd = rsqrtf(q * (1.f / 768.f) - mean * mean + 1e-5f);
#pragma unroll
    for (int e = 0; e < 12; e++)
      acc[r][e] = fmaxf((x[e] - mean) * rstd * g[e] + bb[e], 0.f);
  }

  // Phase D: logits = emb @ W + b, then log_softmax -> ner_prob
  float p[4][25];
#pragma unroll
  for (int r = 0; r < 4; r++)
#pragma unroll
    for (int j = 0; j < 25; j++) p[r][j] = 0.f;
#pragma unroll
  for (int j = 0; j < 25; j++) {
#pragma unroll
    for (int k = 0; k < 3; k++) {
      float4 wv = *(const float4*)(wt + j * 768 + (lane + (k << 6)) * 4);
#pragma unroll
      for (int r = 0; r < 4; r++) {
        p[r][j] = fmaf(acc[r][4 * k + 0], wv.x, p[r][j]);
        p[r][j] = fmaf(acc[r][4 * k + 1], wv.y, p[r][j]);
        p[r][j] = fmaf(acc[r][4 * k + 2], wv.z, p[r][j]);
        p[r][j] = fmaf(acc[r][4 * k + 3], wv.w, p[r][j]);
      }
    }
  }
  float* scw = smem + wid * (64 * 29);
  float bav = (lane < 25) ? badd[lane] : 0.f;
#pragma unroll
  for (int r = 0; r < 4; r++) {
#pragma unroll
    for (int j = 0; j < 25; j++) scw[lane * 29 + j] = p[r][j];
    __syncthreads();
    float lg = bav;
    if (lane < 25) {
      float t0 = 0, t1 = 0, t2 = 0, t3 = 0;
#pragma unroll
      for (int i = 0; i < 64; i += 4) {
        t0 += scw[(i + 0) * 29 + lane];
        t1 += scw[(i + 1) * 29 + lane];
        t2 += scw[(i + 2) * 29 + lane];
        t3 += scw[(i + 3) * 29 + lane];
      }
      lg += (t0 + t1) + (t2 + t3);
    }
    float v = (lane < 25) ? lg : NEGINF;
    float m = wmax(v);
    float e = __expf(v - m);
    float s = wsum(e);
    float lp = v - m - __logf(s);
    if (lane < 25) ner[(size_t)(rowg + r) * 25 + lane] = lp;
    __syncthreads();
  }
}

// ---------------- Kernel 3: CRF forward (logZ + gold score) and Viterbi, concurrent ----------------
__global__ __launch_bounds__(128) void scan_kernel(
    const float* __restrict__ ner, const float* __restrict__ csp,
    const int* __restrict__ labels,
    const float* __restrict__ startt, const float* __restrict__ endt,
    const float* __restrict__ trans,
    float* __restrict__ llh, float* __restrict__ out) {
  const int tid = threadIdx.x;
  const int lane = tid & 63, wid = tid >> 6;
  const int blk = blockIdx.x;
  __shared__ float s_num;
  __shared__ unsigned char hist[512 * 26];

  if (blk < 32) {
    // -------- CRF NLL for batch b: wave1 = gold path score, wave0 = forward logZ --------
    const int b = blk;
    const float* nb = ner + (size_t)b * 512 * 25;
    const int* lb = labels + b * 512;
    if (wid == 1) {
      float a = 0.f;
      for (int t = lane; t < 512; t += 64) a += nb[t * 25 + lb[t]];
      for (int t = lane; t < 511; t += 64) a += trans[lb[t] * 25 + lb[t + 1]];
      a = wsum(a);
      if (lane == 0) s_num = a + startt[lb[0]] + endt[lb[511]];
    }
    float logZ = 0.f;
    if (wid == 0) {
      float Mc[25];  // exp(trans[:,j]) held per lane j
#pragma unroll
      for (int i = 0; i < 25; i++) Mc[i] = (lane < 25) ? __expf(trans[i * 25 + lane]) : 0.f;
      float sc = (lane < 25) ? (startt[lane] + nb[lane]) : NEGINF;
      float em = (lane < 25) ? nb[25 + lane] : 0.f;
      for (int t = 1; t < 512; t++) {
        float emn = (t < 511 && lane < 25) ? nb[(t + 1) * 25 + lane] : 0.f;  // prefetch
        float ms = wmax(sc);
        float E = __expf(sc - ms);  // lanes >=25: exp(-1e30-ms)=0
        float a0 = 0, a1 = 0, a2 = 0, a3 = 0, a4 = 0;
#pragma unroll
        for (int i = 0; i < 25; i += 5) {
          a0 = fmaf(__shfl(E, i + 0), Mc[i + 0], a0);
          a1 = fmaf(__shfl(E, i + 1), Mc[i + 1], a1);
          a2 = fmaf(__shfl(E, i + 2), Mc[i + 2], a2);
          a3 = fmaf(__shfl(E, i + 3), Mc[i + 3], a3);
          a4 = fmaf(__shfl(E, i + 4), Mc[i + 4], a4);
        }
        float acc = ((a0 + a1) + (a2 + a3)) + a4;
        sc = (lane < 25) ? (ms + __logf(acc) + em) : NEGINF;
        em = emn;
      }
      float v = (lane < 25) ? (sc + endt[lane]) : NEGINF;
      float m = wmax(v);
      float ss = wsum(__expf(v - m));
      logZ = m + __logf(ss);
    }
    __syncthreads();
    if (tid == 0) llh[b] = s_num - logZ;
  } else {
    // -------- Viterbi on cos_sim_prob for batch b --------
    const int b = blk - 32;
    if (wid != 0) return;
    const float* cb = csp + (size_t)b * 512 * 25;
    float Tc[25];
#pragma unroll
    for (int i = 0; i < 25; i++) Tc[i] = (lane < 25) ? trans[i * 25 + lane] : 0.f;
    float sc = (lane < 25) ? (startt[lane] + cb[lane]) : NEGINF;
    float em = (lane < 25) ? cb[25 + lane] : 0.f;
    for (int t = 1; t < 512; t++) {
      float emn = (t < 511 && lane < 25) ? cb[(t + 1) * 25 + lane] : 0.f;
      float best = NEGINF; int bi = 0;
#pragma unroll
      for (int i = 0; i < 25; i++) {
        float cand = __shfl(sc, i) + Tc[i];
        if (cand > best) { best = cand; bi = i; }  // strict > keeps first argmax (jnp semantics)
      }
      if (lane < 25) hist[t * 26 + lane] = (unsigned char)bi;
      sc = (lane < 25) ? (best + em) : NEGINF;
      em = emn;
    }
    float fv = (lane < 25) ? (sc + endt[lane]) : NEGINF;
    int idx = lane;
#pragma unroll
    for (int m = 32; m >= 1; m >>= 1) {
      float ov = __shfl_xor(fv, m); int oi = __shfl_xor(idx, m);
      if (ov > fv || (ov == fv && oi < idx)) { fv = ov; idx = oi; }
    }
    int cur = idx;  // uniform across lanes after butterfly
    float* path = out + 1 + (size_t)b * 512;
    if (lane == 0) path[511] = (float)cur;
    for (int t = 511; t >= 1; t--) {
      int h = (lane < 25) ? hist[t * 26 + lane] : 0;
      int prev = __shfl(h, cur);
      if (lane == 0) path[t - 1] = (float)prev;
      cur = prev;
    }
  }
}

// ---------------- Kernel 4: loss = -mean(llh) ----------------
__global__ __launch_bounds__(64) void finalize_kernel(const float* __restrict__ llh,
                                                      float* __restrict__ out) {
  int lane = threadIdx.x;
  float v = (lane < 32) ? llh[lane] : 0.f;
  v = wsum(v);
  if (lane == 0) out[0] = -(v * (1.f / 32.f));
}

extern "C" void kernel_launch(void* const* d_in, const int* in_sizes, int n_in,
                              void* d_out, int out_size, void* d_ws, size_t ws_size,
                              hipStream_t stream) {
  (void)in_sizes; (void)n_in; (void)out_size; (void)ws_size;
  const float* bert   = (const float*)d_in[0];
  const float* oenc   = (const float*)d_in[1];
  const float* cosim  = (const float*)d_in[2];
  const float* decemb = (const float*)d_in[3];
  const int*   labels = (const int*)d_in[4];
  const float* gamma  = (const float*)d_in[5];
  const float* beta   = (const float*)d_in[6];
  const float* Wadd   = (const float*)d_in[7];
  const float* badd   = (const float*)d_in[8];
  const float* startt = (const float*)d_in[9];
  const float* endt   = (const float*)d_in[10];
  const float* trans  = (const float*)d_in[11];
  float* out = (float*)d_out;
  float* ws  = (float*)d_ws;
  float* dec = ws;
  float* wt  = ws + 614400;
  float* ner = ws + 633600;
  float* csp = ws + 1043200;
  float* llh = ws + 1452800;

  prep_kernel<<<832, 256, 0, stream>>>(decemb, gamma, beta, Wadd, dec, wt);
  main_kernel<<<1056, 256, 0, stream>>>(bert, oenc, cosim, gamma, beta, badd, dec, wt, ner, csp);
  scan_kernel<<<64, 128, 0, stream>>>(ner, csp, labels, startt, endt, trans, llh, out);
  finalize_kernel<<<1, 64, 0, stream>>>(llh, out);
}

// Round 2
// 310.390 us; speedup vs baseline: 2.1892x; 2.1892x over previous
//
#include <hip/hip_runtime.h>

// NerTr fused pipeline for MI355X (gfx950).  B=32, S=512, D=768, C=25.
// ws layout (floats): dec[32*25*768] @0, Wt[25*768] @614400, ner[32*512*25] @633600,
//                     llh[32] @1452800.
// out: [0]=loss (f32), [1 + b*512 + t] = viterbi tag (as f32).

#define NEGINF (-1e30f)

__device__ __forceinline__ float wsum(float v) {
#pragma unroll
  for (int m = 32; m >= 1; m >>= 1) v += __shfl_xor(v, m);
  return v;
}
__device__ __forceinline__ float wmax(float v) {
#pragma unroll
  for (int m = 32; m >= 1; m >>= 1) v = fmaxf(v, __shfl_xor(v, m));
  return v;
}
// broadcast lane0 via SALU (no LDS-pipe shfl on the critical chain)
__device__ __forceinline__ float rfl(float x) {
  return __int_as_float(__builtin_amdgcn_readfirstlane(__float_as_int(x)));
}

// in-register argmax over 25 values, first-index tie-break (jnp.argmax semantics),
// tree depth 5 instead of a 25-deep serial compare chain
__device__ __forceinline__ void argmax25(const float c[25], float& bv, int& bi) {
  float v[13]; int x[13];
#pragma unroll
  for (int i = 0; i < 12; i++) {
    bool t = c[2 * i + 1] > c[2 * i];
    v[i] = t ? c[2 * i + 1] : c[2 * i];
    x[i] = t ? 2 * i + 1 : 2 * i;
  }
  v[12] = c[24]; x[12] = 24;
  float w[7]; int y[7];
#pragma unroll
  for (int i = 0; i < 6; i++) {
    bool t = v[2 * i + 1] > v[2 * i];
    w[i] = t ? v[2 * i + 1] : v[2 * i];
    y[i] = t ? x[2 * i + 1] : x[2 * i];
  }
  w[6] = v[12]; y[6] = x[12];
  float u[4]; int z[4];
#pragma unroll
  for (int i = 0; i < 3; i++) {
    bool t = w[2 * i + 1] > w[2 * i];
    u[i] = t ? w[2 * i + 1] : w[2 * i];
    z[i] = t ? y[2 * i + 1] : y[2 * i];
  }
  u[3] = w[6]; z[3] = y[6];
  bool t0 = u[1] > u[0]; float a = t0 ? u[1] : u[0]; int ai = t0 ? z[1] : z[0];
  bool t1 = u[3] > u[2]; float b = t1 ? u[3] : u[2]; int bj = t1 ? z[3] : z[2];
  bool t2 = b > a; bv = t2 ? b : a; bi = t2 ? bj : ai;
}

// ---------------- Kernel 1: LN(decoder_embedding) + transpose W ----------------
__global__ __launch_bounds__(256) void prep_kernel(
    const float* __restrict__ decemb, const float* __restrict__ gamma,
    const float* __restrict__ beta, const float* __restrict__ Wadd,
    float* __restrict__ dec, float* __restrict__ wt) {
  const int blk = blockIdx.x;
  const int tid = threadIdx.x;
  if (blk < 800) {  // one block per (b,c) row of decoder_embedding
    const float* in = decemb + (size_t)blk * 768;
    float x0 = in[tid], x1 = in[tid + 256], x2 = in[tid + 512];
    float s = x0 + x1 + x2, q = x0 * x0 + x1 * x1 + x2 * x2;
    float ws_ = wsum(s), wq = wsum(q);
    __shared__ float sa[4], sq[4];
    int w = tid >> 6, ln = tid & 63;
    if (ln == 0) { sa[w] = ws_; sq[w] = wq; }
    __syncthreads();
    float s1 = sa[0] + sa[1] + sa[2] + sa[3];
    float s2 = sq[0] + sq[1] + sq[2] + sq[3];
    float mean = s1 * (1.f / 768.f);
    float rstd = rsqrtf(s2 * (1.f / 768.f) - mean * mean + 1e-5f);
    float* o = dec + (size_t)blk * 768;
    o[tid]       = (x0 - mean) * rstd * gamma[tid]       + beta[tid];
    o[tid + 256] = (x1 - mean) * rstd * gamma[tid + 256] + beta[tid + 256];
    o[tid + 512] = (x2 - mean) * rstd * gamma[tid + 512] + beta[tid + 512];
  } else {  // transpose W_add [768,25] -> Wt [25,768]
    int gid = (blk - 800) * 256 + tid;
    for (int e = gid; e < 19200; e += 32 * 256) {
      int d = e / 25, j = e - d * 25;
      wt[j * 768 + d] = Wadd[e];
    }
  }
}

// ---------------- Kernel 2: Viterbi blocks (0..31) + fused LN/bmm/LN/logits ----------------
__global__ __launch_bounds__(256) void main_kernel(
    const float* __restrict__ bert, const float* __restrict__ oenc,
    const float* __restrict__ cosim, const float* __restrict__ gamma,
    const float* __restrict__ beta, const float* __restrict__ badd,
    const float* __restrict__ dec, const float* __restrict__ wt,
    const float* __restrict__ startt, const float* __restrict__ endt,
    const float* __restrict__ trans,
    float* __restrict__ ner, float* __restrict__ out) {
  // union'd LDS: fused path needs 4*64*29 floats (29696 B); viterbi needs 16640 B
  __shared__ __align__(16) unsigned char shraw[29696];
  const int tid = threadIdx.x;
  const int lane = tid & 63;
  const int wid = tid >> 6;
  const int blk = blockIdx.x;

  if (blk < 32) {
    // -------- bidirectional Viterbi on softmax(cos_sim), batch b --------
    unsigned char* histF = shraw;           // [256][32] back-pointers t=1..256
    unsigned char* histB = shraw + 8192;    // [255][32] next-pointers t=256..510
    float* fV = (float*)(shraw + 16384);    // fwd state at t=256
    float* bV = fV + 32;                    // bwd state at t=256
    const int b = blk;
    const float* cb = cosim + (size_t)b * 512 * 25;

    if (wid == 0) {
      // forward half: t = 0 .. 256
      float Tc[25];  // column j=lane: trans[i][lane]
#pragma unroll
      for (int i = 0; i < 25; i++) Tc[i] = (lane < 25) ? trans[i * 25 + lane] : 0.f;
      float raw0 = (lane < 25) ? cb[lane] : -400.f;
      float em0;
      { float c0 = rfl(raw0); float E = __expf(raw0 - c0); float S = wsum(E);
        em0 = (lane < 25) ? E * __builtin_amdgcn_rcpf(S) : 0.f; }
      float sc = (lane < 25) ? startt[lane] + em0 : NEGINF;
      float rawA = (lane < 25) ? cb[25 + lane] : -400.f;
      for (int t = 1; t <= 256; t++) {
        float rawB = (t < 256 && lane < 25) ? cb[(t + 1) * 25 + lane] : -400.f;
        float em;  // softmax(row t) — off the sc dependence chain
        { float c0 = rfl(rawA); float E = __expf(rawA - c0); float S = wsum(E);
          em = (lane < 25) ? E * __builtin_amdgcn_rcpf(S) : 0.f; }
        float c[25];
#pragma unroll
        for (int i = 0; i < 25; i++) c[i] = __shfl(sc, i) + Tc[i];
        float bv; int bi;
        argmax25(c, bv, bi);
        if (lane < 25) histF[(t - 1) * 32 + lane] = (unsigned char)bi;
        sc = (lane < 25) ? bv + em : NEGINF;
        rawA = rawB;
      }
      if (lane < 25) fV[lane] = sc;
    } else if (wid == 1) {
      // backward half: t = 511 .. 257 -> bwd state at 256
      float Tr[25];  // row i=lane: trans[lane][j]
#pragma unroll
      for (int j = 0; j < 25; j++) Tr[j] = (lane < 25) ? trans[lane * 25 + j] : 0.f;
      float bwd = (lane < 25) ? endt[lane] : NEGINF;
      float rawA = (lane < 25) ? cb[511 * 25 + lane] : -400.f;
      for (int t = 511; t >= 257; t--) {
        float rawB = (t > 257 && lane < 25) ? cb[(t - 1) * 25 + lane] : -400.f;
        float em;
        { float c0 = rfl(rawA); float E = __expf(rawA - c0); float S = wsum(E);
          em = (lane < 25) ? E * __builtin_amdgcn_rcpf(S) : 0.f; }
        float u = bwd + em;  // lane j holds em_t[j] + bwd_t[j]
        float c[25];
#pragma unroll
        for (int j = 0; j < 25; j++) c[j] = __shfl(u, j) + Tr[j];
        float bv; int bj;
        argmax25(c, bv, bj);
        if (lane < 25) histB[(t - 1 - 256) * 32 + lane] = (unsigned char)bj;
        bwd = (lane < 25) ? bv : NEGINF;
        rawA = rawB;
      }
      if (lane < 25) bV[lane] = bwd;
    }
    __syncthreads();
    if (wid <= 1) {
      // midpoint state: argmax_j(fwd_j + bwd_j), lowest index on tie
      float fv = (lane < 25) ? fV[lane] + bV[lane] : NEGINF;
      int idx = lane;
#pragma unroll
      for (int m = 32; m >= 1; m >>= 1) {
        float ov = __shfl_xor(fv, m); int oi = __shfl_xor(idx, m);
        if (ov > fv || (ov == fv && oi < idx)) { fv = ov; idx = oi; }
      }
      int cur = idx;  // uniform
      float* path = out + 1 + (size_t)b * 512;
      if (wid == 0) {
        if (lane == 0) path[256] = (float)cur;
        for (int t = 256; t >= 1; t--) {
          int h = (lane < 25) ? histF[(t - 1) * 32 + lane] : 0;
          int prev = __shfl(h, cur);
          if (lane == 0) path[t - 1] = (float)prev;
          cur = prev;
        }
      } else {
        for (int t = 256; t <= 510; t++) {
          int h = (lane < 25) ? histB[(t - 256) * 32 + lane] : 0;
          int nx = __shfl(h, cur);
          if (lane == 0) path[t + 1] = (float)nx;
          cur = nx;
        }
      }
    }
    return;
  }

  // ---- fused path: each wave owns 4 consecutive s-rows of one batch ----
  const int fblk = blk - 32;
  const int b = fblk >> 5;
  const int row0 = ((fblk & 31) << 4) + (wid << 2);
  const int rowg = b * 512 + row0;

  float g[12], bb[12];
#pragma unroll
  for (int k = 0; k < 3; k++) {
    float4 gv = *(const float4*)(gamma + (lane + (k << 6)) * 4);
    float4 bv = *(const float4*)(beta + (lane + (k << 6)) * 4);
    g[4 * k + 0] = gv.x; g[4 * k + 1] = gv.y; g[4 * k + 2] = gv.z; g[4 * k + 3] = gv.w;
    bb[4 * k + 0] = bv.x; bb[4 * k + 1] = bv.y; bb[4 * k + 2] = bv.z; bb[4 * k + 3] = bv.w;
  }

  float acc[4][12];
  // Phase A: bf = LN(bert)
#pragma unroll
  for (int r = 0; r < 4; r++) {
    const float* xp = bert + (size_t)(rowg + r) * 768;
    float x[12];
#pragma unroll
    for (int k = 0; k < 3; k++) {
      float4 v = *(const float4*)(xp + (lane + (k << 6)) * 4);
      x[4 * k] = v.x; x[4 * k + 1] = v.y; x[4 * k + 2] = v.z; x[4 * k + 3] = v.w;
    }
    float s = 0.f, q = 0.f;
#pragma unroll
    for (int e = 0; e < 12; e++) { s += x[e]; q += x[e] * x[e]; }
    s = wsum(s); q = wsum(q);
    float mean = s * (1.f / 768.f);
    float rstd = rsqrtf(q * (1.f / 768.f) - mean * mean + 1e-5f);
#pragma unroll
    for (int e = 0; e < 12; e++) acc[r][e] = (x[e] - mean) * rstd * g[e] + bb[e];
  }

  // Phase B: pq = cos_sim @ dec
  float cs[4];
#pragma unroll
  for (int r = 0; r < 4; r++)
    cs[r] = (lane < 25) ? cosim[(size_t)(rowg + r) * 25 + lane] : 0.f;
  float pq[4][12];
#pragma unroll
  for (int r = 0; r < 4; r++)
#pragma unroll
    for (int e = 0; e < 12; e++) pq[r][e] = 0.f;
  const float* db = dec + (size_t)b * 25 * 768;
#pragma unroll 2
  for (int c = 0; c < 25; c++) {
    float dv[12];
#pragma unroll
    for (int k = 0; k < 3; k++) {
      float4 v = *(const float4*)(db + c * 768 + (lane + (k << 6)) * 4);
      dv[4 * k] = v.x; dv[4 * k + 1] = v.y; dv[4 * k + 2] = v.z; dv[4 * k + 3] = v.w;
    }
    float f0 = __shfl(cs[0], c), f1 = __shfl(cs[1], c);
    float f2 = __shfl(cs[2], c), f3 = __shfl(cs[3], c);
#pragma unroll
    for (int e = 0; e < 12; e++) {
      pq[0][e] = fmaf(f0, dv[e], pq[0][e]);
      pq[1][e] = fmaf(f1, dv[e], pq[1][e]);
      pq[2][e] = fmaf(f2, dv[e], pq[2][e]);
      pq[3][e] = fmaf(f3, dv[e], pq[3][e]);
    }
  }

  // Phase C: emb = relu(LN(bf + oenc + pq))
#pragma unroll
  for (int r = 0; r < 4; r++) {
    const float* op = oenc + (size_t)(rowg + r) * 768;
    float x[12];
#pragma unroll
    for (int k = 0; k < 3; k++) {
      float4 v = *(const float4*)(op + (lane + (k << 6)) * 4);
      x[4 * k] = v.x; x[4 * k + 1] = v.y; x[4 * k + 2] = v.z; x[4 * k + 3] = v.w;
    }
    float s = 0.f, q = 0.f;
#pragma unroll
    for (int e = 0; e < 12; e++) {
      x[e] += acc[r][e] + pq[r][e];
      s += x[e]; q += x[e] * x[e];
    }
    s = wsum(s); q = wsum(q);
    float mean = s * (1.f / 768.f);
    float rstd = rsqrtf(q * (1.f / 768.f) - mean * mean + 1e-5f);
#pragma unroll
    for (int e = 0; e < 12; e++)
      acc[r][e] = fmaxf((x[e] - mean) * rstd * g[e] + bb[e], 0.f);
  }

  // Phase D: logits = emb @ W + b, then log_softmax -> ner
  float p[4][25];
#pragma unroll
  for (int r = 0; r < 4; r++)
#pragma unroll
    for (int j = 0; j < 25; j++) p[r][j] = 0.f;
#pragma unroll
  for (int j = 0; j < 25; j++) {
#pragma unroll
    for (int k = 0; k < 3; k++) {
      float4 wv = *(const float4*)(wt + j * 768 + (lane + (k << 6)) * 4);
#pragma unroll
      for (int r = 0; r < 4; r++) {
        p[r][j] = fmaf(acc[r][4 * k + 0], wv.x, p[r][j]);
        p[r][j] = fmaf(acc[r][4 * k + 1], wv.y, p[r][j]);
        p[r][j] = fmaf(acc[r][4 * k + 2], wv.z, p[r][j]);
        p[r][j] = fmaf(acc[r][4 * k + 3], wv.w, p[r][j]);
      }
    }
  }
  float* scw = ((float*)shraw) + wid * (64 * 29);
  float bav = (lane < 25) ? badd[lane] : 0.f;
#pragma unroll
  for (int r = 0; r < 4; r++) {
#pragma unroll
    for (int j = 0; j < 25; j++) scw[lane * 29 + j] = p[r][j];
    __syncthreads();
    float lg = bav;
    if (lane < 25) {
      float t0 = 0, t1 = 0, t2 = 0, t3 = 0;
#pragma unroll
      for (int i = 0; i < 64; i += 4) {
        t0 += scw[(i + 0) * 29 + lane];
        t1 += scw[(i + 1) * 29 + lane];
        t2 += scw[(i + 2) * 29 + lane];
        t3 += scw[(i + 3) * 29 + lane];
      }
      lg += (t0 + t1) + (t2 + t3);
    }
    float v = (lane < 25) ? lg : NEGINF;
    float m = wmax(v);
    float e = __expf(v - m);
    float s = wsum(e);
    float lp = v - m - __logf(s);
    if (lane < 25) ner[(size_t)(rowg + r) * 25 + lane] = lp;
    __syncthreads();
  }
}

// ---------------- Kernel 3: bidirectional CRF forward (logZ) + gold score ----------------
__global__ __launch_bounds__(192) void crf_kernel(
    const float* __restrict__ ner, const int* __restrict__ labels,
    const float* __restrict__ startt, const float* __restrict__ endt,
    const float* __restrict__ trans, float* __restrict__ llh) {
  const int tid = threadIdx.x, lane = tid & 63, wid = tid >> 6;
  const int b = blockIdx.x;
  __shared__ float fV[32], bV[32], s_num;
  const float* nb = ner + (size_t)b * 512 * 25;

  if (wid == 0) {
    // forward lse scan: t = 0 .. 256
    float Mc[25];  // exp(trans[i][lane])
#pragma unroll
    for (int i = 0; i < 25; i++) Mc[i] = (lane < 25) ? __expf(trans[i * 25 + lane]) : 0.f;
    float sc = (lane < 25) ? startt[lane] + nb[lane] : NEGINF;
    float em = (lane < 25) ? nb[25 + lane] : 0.f;
    for (int t = 1; t <= 256; t++) {
      float emn = (t < 256 && lane < 25) ? nb[(t + 1) * 25 + lane] : 0.f;
      float ms = rfl(sc);           // cheap stability offset (SALU broadcast)
      float E = __expf(sc - ms);
      float e_[25];
#pragma unroll
      for (int i = 0; i < 25; i++) e_[i] = __shfl(E, i);
      float a0 = 0, a1 = 0, a2 = 0, a3 = 0, a4 = 0;
#pragma unroll
      for (int i = 0; i < 25; i += 5) {
        a0 = fmaf(e_[i + 0], Mc[i + 0], a0);
        a1 = fmaf(e_[i + 1], Mc[i + 1], a1);
        a2 = fmaf(e_[i + 2], Mc[i + 2], a2);
        a3 = fmaf(e_[i + 3], Mc[i + 3], a3);
        a4 = fmaf(e_[i + 4], Mc[i + 4], a4);
      }
      float acc = ((a0 + a1) + (a2 + a3)) + a4;
      sc = (lane < 25) ? ms + __logf(acc) + em : NEGINF;
      em = emn;
    }
    if (lane < 25) fV[lane] = sc;
  } else if (wid == 1) {
    // backward lse scan: t = 511 .. 257 -> bwd state at 256
    float MrE[25];  // exp(trans[lane][j])
#pragma unroll
    for (int j = 0; j < 25; j++) MrE[j] = (lane < 25) ? __expf(trans[lane * 25 + j]) : 0.f;
    float bwd = (lane < 25) ? endt[lane] : NEGINF;
    float em = (lane < 25) ? nb[511 * 25 + lane] : 0.f;
    for (int t = 511; t >= 257; t--) {
      float emn = (t > 257 && lane < 25) ? nb[(t - 1) * 25 + lane] : 0.f;
      float u = (lane < 25) ? bwd + em : NEGINF;
      float ms = rfl(u);
      float E = __expf(u - ms);
      float e_[25];
#pragma unroll
      for (int j = 0; j < 25; j++) e_[j] = __shfl(E, j);
      float a0 = 0, a1 = 0, a2 = 0, a3 = 0, a4 = 0;
#pragma unroll
      for (int j = 0; j < 25; j += 5) {
        a0 = fmaf(e_[j + 0], MrE[j + 0], a0);
        a1 = fmaf(e_[j + 1], MrE[j + 1], a1);
        a2 = fmaf(e_[j + 2], MrE[j + 2], a2);
        a3 = fmaf(e_[j + 3], MrE[j + 3], a3);
        a4 = fmaf(e_[j + 4], MrE[j + 4], a4);
      }
      float acc = ((a0 + a1) + (a2 + a3)) + a4;
      bwd = (lane < 25) ? ms + __logf(acc) : NEGINF;
      em = emn;
    }
    if (lane < 25) bV[lane] = bwd;
  } else {
    // gold path score
    float a = 0.f;
    const int* lb = labels + b * 512;
    for (int t = lane; t < 512; t += 64) a += nb[t * 25 + lb[t]];
    for (int t = lane; t < 511; t += 64) a += trans[lb[t] * 25 + lb[t + 1]];
    a = wsum(a);
    if (lane == 0) s_num = a + startt[lb[0]] + endt[lb[511]];
  }
  __syncthreads();
  if (wid == 0) {
    float v = (lane < 25) ? fV[lane] + bV[lane] : NEGINF;
    float m = wmax(v);
    float ss = wsum(__expf(v - m));
    if (lane == 0) llh[b] = s_num - (m + __logf(ss));
  }
}

// ---------------- Kernel 4: loss = -mean(llh) ----------------
__global__ __launch_bounds__(64) void finalize_kernel(const float* __restrict__ llh,
                                                      float* __restrict__ out) {
  int lane = threadIdx.x;
  float v = (lane < 32) ? llh[lane] : 0.f;
  v = wsum(v);
  if (lane == 0) out[0] = -(v * (1.f / 32.f));
}

extern "C" void kernel_launch(void* const* d_in, const int* in_sizes, int n_in,
                              void* d_out, int out_size, void* d_ws, size_t ws_size,
                              hipStream_t stream) {
  (void)in_sizes; (void)n_in; (void)out_size; (void)ws_size;
  const float* bert   = (const float*)d_in[0];
  const float* oenc   = (const float*)d_in[1];
  const float* cosim  = (const float*)d_in[2];
  const float* decemb = (const float*)d_in[3];
  const int*   labels = (const int*)d_in[4];
  const float* gamma  = (const float*)d_in[5];
  const float* beta   = (const float*)d_in[6];
  const float* Wadd   = (const float*)d_in[7];
  const float* badd   = (const float*)d_in[8];
  const float* startt = (const float*)d_in[9];
  const float* endt   = (const float*)d_in[10];
  const float* trans  = (const float*)d_in[11];
  float* out = (float*)d_out;
  float* ws  = (float*)d_ws;
  float* dec = ws;
  float* wt  = ws + 614400;
  float* ner = ws + 633600;
  float* llh = ws + 1452800;

  prep_kernel<<<832, 256, 0, stream>>>(decemb, gamma, beta, Wadd, dec, wt);
  main_kernel<<<1056, 256, 0, stream>>>(bert, oenc, cosim, gamma, beta, badd, dec, wt,
                                        startt, endt, trans, ner, out);
  crf_kernel<<<32, 192, 0, stream>>>(ner, labels, startt, endt, trans, llh);
  finalize_kernel<<<1, 64, 0, stream>>>(llh, out);
}

// Round 3
// 197.338 us; speedup vs baseline: 3.4433x; 1.5729x over previous
//
#include <hip/hip_runtime.h>

// NerTr fused pipeline for MI355X (gfx950).  B=32, S=512, D=768, C=25.
// ws layout (floats): dec[32*25*768] @0, Wt[25*768] @614400, ner[32*512*25] @633600.
// out: [0]=loss (f32), [1 + b*512 + t] = viterbi tag (as f32).

#define NEGINF (-1e30f)

__device__ __forceinline__ float wsum(float v) {
#pragma unroll
  for (int m = 32; m >= 1; m >>= 1) v += __shfl_xor(v, m);
  return v;
}
__device__ __forceinline__ float wmax(float v) {
#pragma unroll
  for (int m = 32; m >= 1; m >>= 1) v = fmaxf(v, __shfl_xor(v, m));
  return v;
}
// SALU broadcast of lane0 (no LDS pipe)
__device__ __forceinline__ float rfl(float x) {
  return __int_as_float(__builtin_amdgcn_readfirstlane(__float_as_int(x)));
}
// uniform readlane (VALU->SGPR, no LDS pipe)
__device__ __forceinline__ float rlane(float x, int i) {
  return __int_as_float(__builtin_amdgcn_readlane(__float_as_int(x), i));
}

// in-register argmax over 25 values, first-index tie-break (jnp.argmax semantics)
__device__ __forceinline__ void argmax25(const float c[25], float& bv, int& bi) {
  float v[13]; int x[13];
#pragma unroll
  for (int i = 0; i < 12; i++) {
    bool t = c[2 * i + 1] > c[2 * i];
    v[i] = t ? c[2 * i + 1] : c[2 * i];
    x[i] = t ? 2 * i + 1 : 2 * i;
  }
  v[12] = c[24]; x[12] = 24;
  float w[7]; int y[7];
#pragma unroll
  for (int i = 0; i < 6; i++) {
    bool t = v[2 * i + 1] > v[2 * i];
    w[i] = t ? v[2 * i + 1] : v[2 * i];
    y[i] = t ? x[2 * i + 1] : x[2 * i];
  }
  w[6] = v[12]; y[6] = x[12];
  float u[4]; int z[4];
#pragma unroll
  for (int i = 0; i < 3; i++) {
    bool t = w[2 * i + 1] > w[2 * i];
    u[i] = t ? w[2 * i + 1] : w[2 * i];
    z[i] = t ? y[2 * i + 1] : y[2 * i];
  }
  u[3] = w[6]; z[3] = y[6];
  bool t0 = u[1] > u[0]; float a = t0 ? u[1] : u[0]; int ai = t0 ? z[1] : z[0];
  bool t1 = u[3] > u[2]; float b = t1 ? u[3] : u[2]; int bj = t1 ? z[3] : z[2];
  bool t2 = b > a; bv = t2 ? b : a; bi = t2 ? bj : ai;
}

// ---------------- Kernel 1: LN(decoder_embedding) + transpose W ----------------
__global__ __launch_bounds__(256) void prep_kernel(
    const float* __restrict__ decemb, const float* __restrict__ gamma,
    const float* __restrict__ beta, const float* __restrict__ Wadd,
    float* __restrict__ dec, float* __restrict__ wt) {
  const int blk = blockIdx.x;
  const int tid = threadIdx.x;
  if (blk < 800) {  // one block per (b,c) row of decoder_embedding
    const float* in = decemb + (size_t)blk * 768;
    float x0 = in[tid], x1 = in[tid + 256], x2 = in[tid + 512];
    float s = x0 + x1 + x2, q = x0 * x0 + x1 * x1 + x2 * x2;
    float ws_ = wsum(s), wq = wsum(q);
    __shared__ float sa[4], sq[4];
    int w = tid >> 6, ln = tid & 63;
    if (ln == 0) { sa[w] = ws_; sq[w] = wq; }
    __syncthreads();
    float s1 = sa[0] + sa[1] + sa[2] + sa[3];
    float s2 = sq[0] + sq[1] + sq[2] + sq[3];
    float mean = s1 * (1.f / 768.f);
    float rstd = rsqrtf(s2 * (1.f / 768.f) - mean * mean + 1e-5f);
    float* o = dec + (size_t)blk * 768;
    o[tid]       = (x0 - mean) * rstd * gamma[tid]       + beta[tid];
    o[tid + 256] = (x1 - mean) * rstd * gamma[tid + 256] + beta[tid + 256];
    o[tid + 512] = (x2 - mean) * rstd * gamma[tid + 512] + beta[tid + 512];
  } else {  // transpose W_add [768,25] -> Wt [25,768]
    int gid = (blk - 800) * 256 + tid;
    for (int e = gid; e < 19200; e += 32 * 256) {
      int d = e / 25, j = e - d * 25;
      wt[j * 768 + d] = Wadd[e];
    }
  }
}

// ---------------- Kernel 2: fused LN/bmm/LN/logits (pure streaming) ----------------
__global__ __launch_bounds__(256) void main_kernel(
    const float* __restrict__ bert, const float* __restrict__ oenc,
    const float* __restrict__ cosim, const float* __restrict__ gamma,
    const float* __restrict__ beta, const float* __restrict__ badd,
    const float* __restrict__ dec, const float* __restrict__ wt,
    float* __restrict__ ner, float* __restrict__ out) {
  __shared__ float smem[4 * 64 * 29];
  const int tid = threadIdx.x;
  const int lane = tid & 63;
  const int wid = tid >> 6;
  const int blk = blockIdx.x;
  if (blk == 0 && tid == 0) out[0] = 0.f;  // loss accumulator reset (scan runs after)

  const int b = blk >> 5;
  const int row0 = ((blk & 31) << 4) + (wid << 2);
  const int rowg = b * 512 + row0;

  float g[12], bb[12];
#pragma unroll
  for (int k = 0; k < 3; k++) {
    float4 gv = *(const float4*)(gamma + (lane + (k << 6)) * 4);
    float4 bv = *(const float4*)(beta + (lane + (k << 6)) * 4);
    g[4 * k + 0] = gv.x; g[4 * k + 1] = gv.y; g[4 * k + 2] = gv.z; g[4 * k + 3] = gv.w;
    bb[4 * k + 0] = bv.x; bb[4 * k + 1] = bv.y; bb[4 * k + 2] = bv.z; bb[4 * k + 3] = bv.w;
  }

  float acc[4][12];
  // Phase A: bf = LN(bert)
#pragma unroll
  for (int r = 0; r < 4; r++) {
    const float* xp = bert + (size_t)(rowg + r) * 768;
    float x[12];
#pragma unroll
    for (int k = 0; k < 3; k++) {
      float4 v = *(const float4*)(xp + (lane + (k << 6)) * 4);
      x[4 * k] = v.x; x[4 * k + 1] = v.y; x[4 * k + 2] = v.z; x[4 * k + 3] = v.w;
    }
    float s = 0.f, q = 0.f;
#pragma unroll
    for (int e = 0; e < 12; e++) { s += x[e]; q += x[e] * x[e]; }
    s = wsum(s); q = wsum(q);
    float mean = s * (1.f / 768.f);
    float rstd = rsqrtf(q * (1.f / 768.f) - mean * mean + 1e-5f);
#pragma unroll
    for (int e = 0; e < 12; e++) acc[r][e] = (x[e] - mean) * rstd * g[e] + bb[e];
  }

  // Phase B: pq = cos_sim @ dec
  float cs[4];
#pragma unroll
  for (int r = 0; r < 4; r++)
    cs[r] = (lane < 25) ? cosim[(size_t)(rowg + r) * 25 + lane] : 0.f;
  float pq[4][12];
#pragma unroll
  for (int r = 0; r < 4; r++)
#pragma unroll
    for (int e = 0; e < 12; e++) pq[r][e] = 0.f;
  const float* db = dec + (size_t)b * 25 * 768;
#pragma unroll 2
  for (int c = 0; c < 25; c++) {
    float dv[12];
#pragma unroll
    for (int k = 0; k < 3; k++) {
      float4 v = *(const float4*)(db + c * 768 + (lane + (k << 6)) * 4);
      dv[4 * k] = v.x; dv[4 * k + 1] = v.y; dv[4 * k + 2] = v.z; dv[4 * k + 3] = v.w;
    }
    float f0 = __shfl(cs[0], c), f1 = __shfl(cs[1], c);
    float f2 = __shfl(cs[2], c), f3 = __shfl(cs[3], c);
#pragma unroll
    for (int e = 0; e < 12; e++) {
      pq[0][e] = fmaf(f0, dv[e], pq[0][e]);
      pq[1][e] = fmaf(f1, dv[e], pq[1][e]);
      pq[2][e] = fmaf(f2, dv[e], pq[2][e]);
      pq[3][e] = fmaf(f3, dv[e], pq[3][e]);
    }
  }

  // Phase C: emb = relu(LN(bf + oenc + pq))
#pragma unroll
  for (int r = 0; r < 4; r++) {
    const float* op = oenc + (size_t)(rowg + r) * 768;
    float x[12];
#pragma unroll
    for (int k = 0; k < 3; k++) {
      float4 v = *(const float4*)(op + (lane + (k << 6)) * 4);
      x[4 * k] = v.x; x[4 * k + 1] = v.y; x[4 * k + 2] = v.z; x[4 * k + 3] = v.w;
    }
    float s = 0.f, q = 0.f;
#pragma unroll
    for (int e = 0; e < 12; e++) {
      x[e] += acc[r][e] + pq[r][e];
      s += x[e]; q += x[e] * x[e];
    }
    s = wsum(s); q = wsum(q);
    float mean = s * (1.f / 768.f);
    float rstd = rsqrtf(q * (1.f / 768.f) - mean * mean + 1e-5f);
#pragma unroll
    for (int e = 0; e < 12; e++)
      acc[r][e] = fmaxf((x[e] - mean) * rstd * g[e] + bb[e], 0.f);
  }

  // Phase D: logits = emb @ W + b, then log_softmax -> ner
  float p[4][25];
#pragma unroll
  for (int r = 0; r < 4; r++)
#pragma unroll
    for (int j = 0; j < 25; j++) p[r][j] = 0.f;
#pragma unroll
  for (int j = 0; j < 25; j++) {
#pragma unroll
    for (int k = 0; k < 3; k++) {
      float4 wv = *(const float4*)(wt + j * 768 + (lane + (k << 6)) * 4);
#pragma unroll
      for (int r = 0; r < 4; r++) {
        p[r][j] = fmaf(acc[r][4 * k + 0], wv.x, p[r][j]);
        p[r][j] = fmaf(acc[r][4 * k + 1], wv.y, p[r][j]);
        p[r][j] = fmaf(acc[r][4 * k + 2], wv.z, p[r][j]);
        p[r][j] = fmaf(acc[r][4 * k + 3], wv.w, p[r][j]);
      }
    }
  }
  float* scw = smem + wid * (64 * 29);
  float bav = (lane < 25) ? badd[lane] : 0.f;
#pragma unroll
  for (int r = 0; r < 4; r++) {
#pragma unroll
    for (int j = 0; j < 25; j++) scw[lane * 29 + j] = p[r][j];
    __syncthreads();
    float lg = bav;
    if (lane < 25) {
      float t0 = 0, t1 = 0, t2 = 0, t3 = 0;
#pragma unroll
      for (int i = 0; i < 64; i += 4) {
        t0 += scw[(i + 0) * 29 + lane];
        t1 += scw[(i + 1) * 29 + lane];
        t2 += scw[(i + 2) * 29 + lane];
        t3 += scw[(i + 3) * 29 + lane];
      }
      lg += (t0 + t1) + (t2 + t3);
    }
    float v = (lane < 25) ? lg : NEGINF;
    float m = wmax(v);
    float e = __expf(v - m);
    float s = wsum(e);
    float lp = v - m - __logf(s);
    if (lane < 25) ner[(size_t)(rowg + r) * 25 + lane] = lp;
    __syncthreads();
  }
}

// ---------------- Kernel 3: CRF (blocks 0..31) + Viterbi (blocks 32..63) ----------------
// All sequential chains use v_readlane (VALU) — zero ds_bpermute on the critical path.
__global__ __launch_bounds__(256) void scan_kernel(
    const float* __restrict__ ner, const float* __restrict__ cosim,
    const int* __restrict__ labels,
    const float* __restrict__ startt, const float* __restrict__ endt,
    const float* __restrict__ trans, float* __restrict__ out) {
  const int tid = threadIdx.x, lane = tid & 63, wid = tid >> 6;
  const int blk = blockIdx.x;
  // union LDS: viterbi needs em[512*25]f + histF[256*26] + histB[255*26] + fV/bV
  __shared__ __align__(16) unsigned char shraw[64768];

  if (blk < 32) {
    // ======== CRF NLL for batch b ========
    const int b = blk;
    const float* nb = ner + (size_t)b * 512 * 25;
    float* fV = (float*)shraw;
    float* bV = fV + 32;
    float* s_num = bV + 32;
    if (wid == 0) {
      // forward lse scan t = 0..256
      float Mc[25];  // exp(trans[i][lane])
#pragma unroll
      for (int i = 0; i < 25; i++) Mc[i] = (lane < 25) ? __expf(trans[i * 25 + lane]) : 0.f;
      float sc = (lane < 25) ? startt[lane] + nb[lane] : NEGINF;
      float em = (lane < 25) ? nb[25 + lane] : 0.f;
      for (int t = 1; t <= 256; t++) {
        float emn = (t < 256 && lane < 25) ? nb[(t + 1) * 25 + lane] : 0.f;  // prefetch
        float ms = rfl(sc);
        float E = __expf(sc - ms);
        float a0 = 0, a1 = 0, a2 = 0, a3 = 0, a4 = 0;
#pragma unroll
        for (int i = 0; i < 25; i += 5) {
          a0 = fmaf(rlane(E, i + 0), Mc[i + 0], a0);
          a1 = fmaf(rlane(E, i + 1), Mc[i + 1], a1);
          a2 = fmaf(rlane(E, i + 2), Mc[i + 2], a2);
          a3 = fmaf(rlane(E, i + 3), Mc[i + 3], a3);
          a4 = fmaf(rlane(E, i + 4), Mc[i + 4], a4);
        }
        float acc = ((a0 + a1) + (a2 + a3)) + a4;
        sc = (lane < 25) ? ms + __logf(acc) + em : NEGINF;
        em = emn;
      }
      if (lane < 25) fV[lane] = sc;
    } else if (wid == 1) {
      // backward lse scan t = 511..257
      float MrE[25];  // exp(trans[lane][j])
#pragma unroll
      for (int j = 0; j < 25; j++) MrE[j] = (lane < 25) ? __expf(trans[lane * 25 + j]) : 0.f;
      float bwd = (lane < 25) ? endt[lane] : NEGINF;
      float em = (lane < 25) ? nb[511 * 25 + lane] : 0.f;
      for (int t = 511; t >= 257; t--) {
        float emn = (t > 257 && lane < 25) ? nb[(t - 1) * 25 + lane] : 0.f;
        float u = (lane < 25) ? bwd + em : NEGINF;
        float ms = rfl(u);
        float E = __expf(u - ms);
        float a0 = 0, a1 = 0, a2 = 0, a3 = 0, a4 = 0;
#pragma unroll
        for (int j = 0; j < 25; j += 5) {
          a0 = fmaf(rlane(E, j + 0), MrE[j + 0], a0);
          a1 = fmaf(rlane(E, j + 1), MrE[j + 1], a1);
          a2 = fmaf(rlane(E, j + 2), MrE[j + 2], a2);
          a3 = fmaf(rlane(E, j + 3), MrE[j + 3], a3);
          a4 = fmaf(rlane(E, j + 4), MrE[j + 4], a4);
        }
        float acc = ((a0 + a1) + (a2 + a3)) + a4;
        bwd = (lane < 25) ? ms + __logf(acc) : NEGINF;
        em = emn;
      }
      if (lane < 25) bV[lane] = bwd;
    } else if (wid == 2) {
      // gold path score
      float a = 0.f;
      const int* lb = labels + b * 512;
      for (int t = lane; t < 512; t += 64) a += nb[t * 25 + lb[t]];
      for (int t = lane; t < 511; t += 64) a += trans[lb[t] * 25 + lb[t + 1]];
      a = wsum(a);
      if (lane == 0) *s_num = a + startt[lb[0]] + endt[lb[511]];
    }
    __syncthreads();
    if (wid == 0) {
      float v = (lane < 25) ? fV[lane] + bV[lane] : NEGINF;
      float m = wmax(v);
      float ss = wsum(__expf(v - m));
      float llh = *s_num - (m + __logf(ss));
      if (lane == 0) atomicAdd(out, -llh * (1.f / 32.f));
    }
    return;
  }

  // ======== bidirectional Viterbi on softmax(cos_sim), batch b ========
  const int b = blk - 32;
  float* em = (float*)shraw;                     // [512][25] packed, 51200 B
  unsigned char* histF = shraw + 51200;          // [256][26]
  unsigned char* histB = shraw + 57856;          // [255][26]
  float* fV = (float*)(shraw + 64488);
  float* bV = fV + 32;
  const float* cb = cosim + (size_t)b * 512 * 25;

  // cooperative coalesced load cosim[b] -> LDS (3200 float4)
  {
    float4* em4 = (float4*)em;
    const float4* cb4 = (const float4*)cb;
    for (int i = tid; i < 3200; i += 256) em4[i] = cb4[i];
  }
  __syncthreads();
  // per-thread row softmax in place (rows tid, tid+256; stride 25 is odd -> bank-clean)
#pragma unroll
  for (int rr = 0; rr < 2; rr++) {
    const int r = tid + (rr << 8);
    float v[25];
#pragma unroll
    for (int k = 0; k < 25; k++) v[k] = em[r * 25 + k];
    float m01 = v[0];
#pragma unroll
    for (int k = 1; k < 25; k++) m01 = fmaxf(m01, v[k]);
    float s = 0.f;
#pragma unroll
    for (int k = 0; k < 25; k++) { v[k] = __expf(v[k] - m01); s += v[k]; }
    float rinv = __builtin_amdgcn_rcpf(s);
#pragma unroll
    for (int k = 0; k < 25; k++) em[r * 25 + k] = v[k] * rinv;
  }
  __syncthreads();

  const int eml = (lane < 25) ? lane : 0;  // clamp lane for LDS reads
  if (wid == 0) {
    // forward Viterbi: t = 0..256
    float Tc[25];  // trans[i][lane]
#pragma unroll
    for (int i = 0; i < 25; i++) Tc[i] = (lane < 25) ? trans[i * 25 + lane] : 0.f;
    float sc = (lane < 25) ? startt[lane] + em[eml] : NEGINF;
    float emA = em[25 + eml];
    for (int t = 1; t <= 256; t++) {
      float emB = (t < 256) ? em[(t + 1) * 25 + eml] : 0.f;  // prefetch (LDS)
      float c[25];
#pragma unroll
      for (int i = 0; i < 25; i++) c[i] = rlane(sc, i) + Tc[i];
      float bv; int bi;
      argmax25(c, bv, bi);
      if (lane < 25) histF[(t - 1) * 26 + lane] = (unsigned char)bi;
      sc = (lane < 25) ? bv + emA : NEGINF;
      emA = emB;
    }
    if (lane < 25) fV[lane] = sc;
  } else if (wid == 1) {
    // backward Viterbi: t = 511..257
    float Tr[25];  // trans[lane][j]
#pragma unroll
    for (int j = 0; j < 25; j++) Tr[j] = (lane < 25) ? trans[lane * 25 + j] : 0.f;
    float bwd = (lane < 25) ? endt[lane] : NEGINF;
    float emA = em[511 * 25 + eml];
    for (int t = 511; t >= 257; t--) {
      float emB = (t > 257) ? em[(t - 1) * 25 + eml] : 0.f;
      float u = bwd + emA;
      float c[25];
#pragma unroll
      for (int j = 0; j < 25; j++) c[j] = rlane(u, j) + Tr[j];
      float bv; int bj;
      argmax25(c, bv, bj);
      if (lane < 25) histB[(t - 1 - 256) * 26 + lane] = (unsigned char)bj;
      bwd = (lane < 25) ? bv : NEGINF;
      emA = emB;
    }
    if (lane < 25) bV[lane] = bwd;
  }
  __syncthreads();
  if (wid <= 1) {
    // midpoint: argmax_j(fwd_j + bwd_j), first index on tie
    float fv = (lane < 25) ? fV[lane] + bV[lane] : NEGINF;
    int idx = lane;
#pragma unroll
    for (int m = 32; m >= 1; m >>= 1) {
      float ov = __shfl_xor(fv, m); int oi = __shfl_xor(idx, m);
      if (ov > fv || (ov == fv && oi < idx)) { fv = ov; idx = oi; }
    }
    int cur = idx;  // uniform
    float* path = out + 1 + (size_t)b * 512;
    if (wid == 0) {
      if (lane == 0) path[256] = (float)cur;
      int h = (lane < 25) ? histF[255 * 26 + lane] : 0;
      for (int t = 256; t >= 1; t--) {
        int hn = (t > 1 && lane < 25) ? histF[(t - 2) * 26 + lane] : 0;  // prefetch
        int prev = __builtin_amdgcn_readlane(h, cur);
        if (lane == 0) path[t - 1] = (float)prev;
        cur = prev; h = hn;
      }
    } else {
      int h = (lane < 25) ? histB[lane] : 0;  // entry for t=257
      for (int t = 256; t <= 510; t++) {
        int hn = (t < 510 && lane < 25) ? histB[(t - 255) * 26 + lane] : 0;
        int nx = __builtin_amdgcn_readlane(h, cur);
        if (lane == 0) path[t + 1] = (float)nx;
        cur = nx; h = hn;
      }
    }
  }
}

extern "C" void kernel_launch(void* const* d_in, const int* in_sizes, int n_in,
                              void* d_out, int out_size, void* d_ws, size_t ws_size,
                              hipStream_t stream) {
  (void)in_sizes; (void)n_in; (void)out_size; (void)ws_size;
  const float* bert   = (const float*)d_in[0];
  const float* oenc   = (const float*)d_in[1];
  const float* cosim  = (const float*)d_in[2];
  const float* decemb = (const float*)d_in[3];
  const int*   labels = (const int*)d_in[4];
  const float* gamma  = (const float*)d_in[5];
  const float* beta   = (const float*)d_in[6];
  const float* Wadd   = (const float*)d_in[7];
  const float* badd   = (const float*)d_in[8];
  const float* startt = (const float*)d_in[9];
  const float* endt   = (const float*)d_in[10];
  const float* trans  = (const float*)d_in[11];
  float* out = (float*)d_out;
  float* ws  = (float*)d_ws;
  float* dec = ws;
  float* wt  = ws + 614400;
  float* ner = ws + 633600;

  prep_kernel<<<832, 256, 0, stream>>>(decemb, gamma, beta, Wadd, dec, wt);
  main_kernel<<<1024, 256, 0, stream>>>(bert, oenc, cosim, gamma, beta, badd, dec, wt, ner, out);
  scan_kernel<<<64, 256, 0, stream>>>(ner, cosim, labels, startt, endt, trans, out);
}